// Round 10
// baseline (179.843 us; speedup 1.0000x reference)
//
#include <hip/hip_runtime.h>
#include <math.h>

#define NB   32
#define CC   512
#define DD   2048
#define HWP  196
#define NHW  6272
#define HID  256

typedef _Float16 h8 __attribute__((ext_vector_type(8)));
typedef _Float16 h4 __attribute__((ext_vector_type(4)));
typedef float    f4 __attribute__((ext_vector_type(4)));
union F4H8 { f4 f; h8 h; };

// fp16 index into fragment-layout tensor for (row j, col k), K=256, 64-row j-tiles.
__device__ __forceinline__ int fragIdx(int j, int k) {
    return ((j >> 6) << 14) + (((k >> 5) * 4 + ((j & 63) >> 4)) << 9)
         + (((((k >> 3) & 3) << 4) + (j & 15)) << 3) + (k & 7);
}

// ================= prep: 864 blocks x 256 =================
// 0..511: hglb partials; 512..607: W2F/W1F frag pack; 608..863: lf transpose
__global__ __launch_bounds__(256) void prep_kernel(const float* __restrict__ lf,
                                                   const float* __restrict__ gf,
                                                   const float* __restrict__ W1,
                                                   const float* __restrict__ W2,
                                                   float* __restrict__ hpart,
                                                   _Float16* __restrict__ W2F,
                                                   _Float16* __restrict__ W1F,
                                                   _Float16* __restrict__ lf16T) {
    int bid = blockIdx.x, tid = threadIdx.x;
    if (bid < 512) {
        int i = bid >> 4, ky = bid & 15, k = tid;
        const float* g = gf + (size_t)i * DD + ky * 128;
        const float* w = W1 + (size_t)(ky * 128) * HID + k;
        float acc = 0.f;
        #pragma unroll 8
        for (int r = 0; r < 128; r++) acc = fmaf(g[r], w[(size_t)r * HID], acc);
        hpart[((size_t)i * 16 + ky) * HID + k] = acc;
    } else if (bid < 608) {
        int tg = (bid - 512) * 256 + tid;            // 0..24575
        if (tg < 8192) {
            int t = tg, F = t >> 6, l = t & 63;
            int k2t = F >> 3, ks = F & 7;
            int kb = ks * 32 + (l >> 4) * 8;
            int n  = k2t * 16 + (l & 15);
            _Float16* o = W2F + (size_t)t * 8;
            #pragma unroll
            for (int j = 0; j < 8; j++) o[j] = (_Float16)W2[(size_t)(kb + j) * HID + n];
        } else {
            int t = tg - 8192, F = t >> 6, l = t & 63;
            int k2t = F >> 4, ks = F & 15;
            int kb = ks * 32 + (l >> 4) * 8;
            int n  = k2t * 16 + (l & 15);
            const float* W1c = W1 + (size_t)DD * HID;
            _Float16* o = W1F + (size_t)t * 8;
            #pragma unroll
            for (int j = 0; j < 8; j++) o[j] = (_Float16)W1c[(size_t)(kb + j) * HID + n];
        }
    } else {
        __shared__ _Float16 sT[64][HWP + 4];
        int b = bid - 608;                           // 0..255
        int n = b >> 3, c0 = (b & 7) * 64;
        for (int task = tid; task < 64 * 49; task += 256) {
            int c = task / 49, f = task - c * 49;
            f4 v = *(const f4*)&lf[((size_t)n * CC + c0 + c) * HWP + f * 4];
            h4 o = { (_Float16)v.x, (_Float16)v.y, (_Float16)v.z, (_Float16)v.w };
            *(h4*)&sT[c][f * 4] = o;
        }
        __syncthreads();
        for (int task = tid; task < 8 * HWP; task += 256) {
            int ch = task / HWP, p = task - ch * HWP;
            h8 o;
            #pragma unroll
            for (int cc = 0; cc < 8; cc++) o[cc] = sT[ch * 8 + cc][p];
            *(h8*)&lf16T[((size_t)(n * HWP + p)) * CC + c0 + ch * 8] = o;
        }
    }
}

// ================= hlocF: h_loc = lf16T @ W1[D:], MFMA, frag-layout output =================
__global__ __launch_bounds__(256, 2) void hlocF_kernel(const _Float16* __restrict__ lf16T,
                                                       const _Float16* __restrict__ W1F,
                                                       const float* __restrict__ hpart,
                                                       const float* __restrict__ b1,
                                                       _Float16* __restrict__ g16,
                                                       _Float16* __restrict__ hF) {
    if (blockIdx.x == 196) {
        int kh = blockIdx.y;
        for (int x = threadIdx.x; x < 16 * HID; x += 256) {
            int i = kh * 16 + (x >> 8), k = x & 255;
            float s = b1[k];
            #pragma unroll
            for (int ky = 0; ky < 16; ky++) s += hpart[((size_t)i * 16 + ky) * HID + k];
            g16[(size_t)i * HID + k] = (_Float16)s;
        }
        return;
    }
    __shared__ _Float16 sLf[32][CC + 16];
    int tid = threadIdx.x;
    int w = tid >> 6, l = tid & 63, quad = l >> 4, ln = l & 15;
    int j0 = blockIdx.x * 32;
    int khalf = blockIdx.y;

    #pragma unroll
    for (int s = 0; s < 8; s++) {
        int y = s * 256 + tid;
        int row = y >> 6, col = (y & 63) * 8;
        h8 v = *(const h8*)&lf16T[(size_t)(j0 + row) * CC + col];
        *(h8*)&sLf[row][col] = v;
    }

    F4H8 Af[32];
    {
        const f4* src = (const f4*)W1F + l;
        #pragma unroll
        for (int mt = 0; mt < 2; mt++)
            #pragma unroll
            for (int ks = 0; ks < 16; ks++)
                Af[mt * 16 + ks].f = src[(size_t)((khalf * 8 + w * 2 + mt) * 16 + ks) * 64];
    }
    __syncthreads();

    f4 acc[4] = {};
    #pragma unroll
    for (int ks = 0; ks < 16; ks++) {
        h8 bF[2];
        #pragma unroll
        for (int nt = 0; nt < 2; nt++)
            bF[nt] = *(const h8*)&sLf[nt * 16 + ln][ks * 32 + quad * 8];
        #pragma unroll
        for (int mt = 0; mt < 2; mt++)
            #pragma unroll
            for (int nt = 0; nt < 2; nt++)
                acc[mt * 2 + nt] = __builtin_amdgcn_mfma_f32_16x16x32_f16(Af[mt * 16 + ks].h, bF[nt], acc[mt * 2 + nt], 0, 0, 0);
    }

    #pragma unroll
    for (int mt = 0; mt < 2; mt++)
        #pragma unroll
        for (int nt = 0; nt < 2; nt++)
            #pragma unroll
            for (int r = 0; r < 4; r++) {
                int j  = j0 + nt * 16 + ln;
                int k2 = khalf * 128 + w * 32 + mt * 16 + quad * 4 + r;
                hF[fragIdx(j, k2)] = (_Float16)acc[mt * 2 + nt][r];
            }
}

// ================= score: registers-only, no LDS / barriers / atomics =================
// 784 blocks x 128 thr (2 waves); wave task = (jt 0..97, i-pair 0..15).
// Per wave: hF tile (64j x 256k1) resident in 32 frags (128 VGPR); k2 swept in 8
// slices of 32 with W2 frags streamed 2/ks from L2; hz = relu(hv+g) computed once
// per (sl,i,ks), feeds 8 MFMAs; W3-dot partial accumulated per slice in 8 floats.
__global__ __launch_bounds__(128, 2) void score_kernel(const _Float16* __restrict__ hF,
                                                       const _Float16* __restrict__ g16,
                                                       const _Float16* __restrict__ W2F,
                                                       const float* __restrict__ b2,
                                                       const float* __restrict__ W3,
                                                       float* __restrict__ scores) {
    int tid = threadIdx.x, w = tid >> 6, l = tid & 63, quad = l >> 4, ln = l & 15;
    int task = blockIdx.x * 2 + w;        // 0..1567
    int jt = task >> 4;                   // 0..97
    int i0 = (task & 15) * 2;             // 0,2,..,30

    // resident hF tile: 32 B-frags
    F4H8 hv[32];
    {
        const f4* hbase = (const f4*)(hF + (size_t)jt * 16384) + l;
        #pragma unroll
        for (int q = 0; q < 32; q++) hv[q].f = hbase[q * 64];
    }

    float score[2][4] = {};               // [ii][nt]
    const f4* asrc = (const f4*)W2F + l;

    #pragma unroll 1
    for (int sl = 0; sl < 8; sl++) {
        f4 b2v0 = *(const f4*)&b2[sl * 32 + quad * 4];
        f4 b2v1 = *(const f4*)&b2[sl * 32 + 16 + quad * 4];
        f4 w3v0 = *(const f4*)&W3[sl * 32 + quad * 4];
        f4 w3v1 = *(const f4*)&W3[sl * 32 + 16 + quad * 4];
        #pragma unroll
        for (int ii = 0; ii < 2; ii++) {
            const _Float16* gbase = g16 + (size_t)(i0 + ii) * HID + quad * 8;
            f4 acc[4][2] = {};            // [nt][mt]
            #pragma unroll
            for (int ks = 0; ks < 8; ks++) {
                F4H8 af0, af1;
                af0.f = asrc[(size_t)(sl * 16 + ks) * 64];
                af1.f = asrc[(size_t)(sl * 16 + 8 + ks) * 64];
                h8 gq = *(const h8*)(gbase + ks * 32);
                h8 z = {};
                #pragma unroll
                for (int nt = 0; nt < 4; nt++) {
                    h8 hz = __builtin_elementwise_max(hv[ks * 4 + nt].h + gq, z);
                    acc[nt][0] = __builtin_amdgcn_mfma_f32_16x16x32_f16(af0.h, hz, acc[nt][0], 0, 0, 0);
                    acc[nt][1] = __builtin_amdgcn_mfma_f32_16x16x32_f16(af1.h, hz, acc[nt][1], 0, 0, 0);
                }
            }
            // partial epilogue for this (sl, ii): relu(+b2) . W3 over 32 k2
            #pragma unroll
            for (int nt = 0; nt < 4; nt++) {
                float s = fmaxf(acc[nt][0][0] + b2v0.x, 0.f) * w3v0.x
                        + fmaxf(acc[nt][0][1] + b2v0.y, 0.f) * w3v0.y
                        + fmaxf(acc[nt][0][2] + b2v0.z, 0.f) * w3v0.z
                        + fmaxf(acc[nt][0][3] + b2v0.w, 0.f) * w3v0.w
                        + fmaxf(acc[nt][1][0] + b2v1.x, 0.f) * w3v1.x
                        + fmaxf(acc[nt][1][1] + b2v1.y, 0.f) * w3v1.y
                        + fmaxf(acc[nt][1][2] + b2v1.z, 0.f) * w3v1.z
                        + fmaxf(acc[nt][1][3] + b2v1.w, 0.f) * w3v1.w;
                score[ii][nt] += s;
            }
        }
    }

    // final: reduce over quads (k2 groups), each (i,j) written by exactly one lane
    #pragma unroll
    for (int ii = 0; ii < 2; ii++)
        #pragma unroll
        for (int nt = 0; nt < 4; nt++) {
            float s = score[ii][nt];
            s += __shfl_xor(s, 16, 64);
            s += __shfl_xor(s, 32, 64);
            if (quad == 0)
                scores[(size_t)(i0 + ii) * NHW + jt * 64 + nt * 16 + ln] = s;
        }
}

// ================= reduce: per-row max, masked log-mean-exp =================
// b3 cancels analytically in mi — omitted (verified R9).
__global__ __launch_bounds__(1024) void reduce_kernel(const float* __restrict__ scores,
                                                      float* __restrict__ out) {
    int i = blockIdx.x, tid = threadIdx.x;
    const float* row = scores + (size_t)i * NHW;
    const f4* row4 = (const f4*)row;                 // 1568 f4
    __shared__ float sW[16], sW2[16], sval[2];
    float mx = -1e30f;
    for (int q = tid; q < 1568; q += 1024) {
        f4 v = row4[q];
        mx = fmaxf(mx, fmaxf(fmaxf(v.x, v.y), fmaxf(v.z, v.w)));
    }
    #pragma unroll
    for (int off = 32; off > 0; off >>= 1) mx = fmaxf(mx, __shfl_down(mx, off, 64));
    if ((tid & 63) == 0) sW[tid >> 6] = mx;
    __syncthreads();
    if (tid == 0) {
        float m = sW[0];
        for (int c = 1; c < 16; c++) m = fmaxf(m, sW[c]);
        sval[0] = m;
    }
    __syncthreads();
    mx = sval[0];
    int q0 = i * 49, q1 = q0 + 49;
    float tot = 0.f, ownv = 0.f;
    for (int q = tid; q < 1568; q += 1024) {
        f4 v = row4[q];
        float e = expf(v.x - mx) + expf(v.y - mx) + expf(v.z - mx) + expf(v.w - mx);
        tot += e;
        if (q >= q0 && q < q1) ownv += e;
    }
    #pragma unroll
    for (int off = 32; off > 0; off >>= 1) {
        tot  += __shfl_down(tot, off, 64);
        ownv += __shfl_down(ownv, off, 64);
    }
    if ((tid & 63) == 0) { sW[tid >> 6] = tot; sW2[tid >> 6] = ownv; }
    __syncthreads();
    if (tid == 0) {
        float t = 0.f, o = 0.f;
        for (int c = 0; c < 16; c++) { t += sW[c]; o += sW2[c]; }
        float neg_mean = (t - o) / (float)(NHW - HWP) + 1e-10f;
        sval[1] = mx + logf(neg_mean);
    }
    __syncthreads();
    float sub = sval[1];
    if (tid < HWP) out[(size_t)i * HWP + tid] = row[i * HWP + tid] - sub;
}

extern "C" void kernel_launch(void* const* d_in, const int* in_sizes, int n_in,
                              void* d_out, int out_size, void* d_ws, size_t ws_size,
                              hipStream_t stream) {
    const float* lf = (const float*)d_in[0];
    const float* gf = (const float*)d_in[1];
    const float* W1 = (const float*)d_in[2];
    const float* b1 = (const float*)d_in[3];
    const float* W2 = (const float*)d_in[4];
    const float* b2 = (const float*)d_in[5];
    const float* W3 = (const float*)d_in[6];
    float* out = (float*)d_out;

    char* ws = (char*)d_ws;
    _Float16* hF     = (_Float16*)ws;                      // 3,211,264 B
    _Float16* g16    = (_Float16*)(ws + 3211264);          // 16 KB
    _Float16* W2F    = (_Float16*)(ws + 3227648);          // 128 KB
    _Float16* W1F    = (_Float16*)(ws + 3358720);          // 256 KB
    _Float16* lf16T  = (_Float16*)(ws + 3620864);          // 6,422,528 B
    float*    scores = (float*)   (ws + 10043392);         // 802,816 B
    float*    hpart  = (float*)   (ws + 10846208);         // 524,288 B

    hipLaunchKernelGGL(prep_kernel, dim3(864), dim3(256), 0, stream,
                       lf, gf, W1, W2, hpart, W2F, W1F, lf16T);
    hipLaunchKernelGGL(hlocF_kernel, dim3(197, 2), dim3(256), 0, stream,
                       lf16T, W1F, hpart, b1, g16, hF);
    hipLaunchKernelGGL(score_kernel, dim3(784), dim3(128), 0, stream,
                       hF, g16, W2F, b2, W3, scores);
    hipLaunchKernelGGL(reduce_kernel, dim3(NB), dim3(1024), 0, stream, scores, out);
}

// Round 11
// 151.886 us; speedup vs baseline: 1.1841x; 1.1841x over previous
//
#include <hip/hip_runtime.h>
#include <math.h>

#define NB   32
#define CC   512
#define DD   2048
#define HWP  196
#define NHW  6272
#define HID  256

typedef _Float16 h8 __attribute__((ext_vector_type(8)));
typedef _Float16 h4 __attribute__((ext_vector_type(4)));
typedef float    f4 __attribute__((ext_vector_type(4)));
union F4H8 { f4 f; h8 h; };

// fp16 index into fragment-layout tensor for (row j, col k), K=256, 64-row j-tiles.
__device__ __forceinline__ int fragIdx(int j, int k) {
    return ((j >> 6) << 14) + (((k >> 5) * 4 + ((j & 63) >> 4)) << 9)
         + (((((k >> 3) & 3) << 4) + (j & 15)) << 3) + (k & 7);
}

// ================= prep: 864 blocks x 256 =================
// 0..511: hglb partials; 512..607: W2F/W1F frag pack; 608..863: lf transpose
__global__ __launch_bounds__(256) void prep_kernel(const float* __restrict__ lf,
                                                   const float* __restrict__ gf,
                                                   const float* __restrict__ W1,
                                                   const float* __restrict__ W2,
                                                   float* __restrict__ hpart,
                                                   _Float16* __restrict__ W2F,
                                                   _Float16* __restrict__ W1F,
                                                   _Float16* __restrict__ lf16T) {
    int bid = blockIdx.x, tid = threadIdx.x;
    if (bid < 512) {
        int i = bid >> 4, ky = bid & 15, k = tid;
        const float* g = gf + (size_t)i * DD + ky * 128;
        const float* w = W1 + (size_t)(ky * 128) * HID + k;
        float a0 = 0.f, a1 = 0.f, a2 = 0.f, a3 = 0.f;   // 4-way ILP
        #pragma unroll 8
        for (int r = 0; r < 128; r += 4) {
            a0 = fmaf(g[r + 0], w[(size_t)(r + 0) * HID], a0);
            a1 = fmaf(g[r + 1], w[(size_t)(r + 1) * HID], a1);
            a2 = fmaf(g[r + 2], w[(size_t)(r + 2) * HID], a2);
            a3 = fmaf(g[r + 3], w[(size_t)(r + 3) * HID], a3);
        }
        hpart[((size_t)i * 16 + ky) * HID + k] = (a0 + a1) + (a2 + a3);
    } else if (bid < 608) {
        int tg = (bid - 512) * 256 + tid;            // 0..24575
        if (tg < 8192) {
            int t = tg, F = t >> 6, l = t & 63;
            int k2t = F >> 3, ks = F & 7;
            int kb = ks * 32 + (l >> 4) * 8;
            int n  = k2t * 16 + (l & 15);
            _Float16* o = W2F + (size_t)t * 8;
            #pragma unroll
            for (int j = 0; j < 8; j++) o[j] = (_Float16)W2[(size_t)(kb + j) * HID + n];
        } else {
            int t = tg - 8192, F = t >> 6, l = t & 63;
            int k2t = F >> 4, ks = F & 15;
            int kb = ks * 32 + (l >> 4) * 8;
            int n  = k2t * 16 + (l & 15);
            const float* W1c = W1 + (size_t)DD * HID;
            _Float16* o = W1F + (size_t)t * 8;
            #pragma unroll
            for (int j = 0; j < 8; j++) o[j] = (_Float16)W1c[(size_t)(kb + j) * HID + n];
        }
    } else {
        __shared__ _Float16 sT[64][HWP + 4];
        int b = bid - 608;                           // 0..255
        int n = b >> 3, c0 = (b & 7) * 64;
        for (int task = tid; task < 64 * 49; task += 256) {
            int c = task / 49, f = task - c * 49;
            f4 v = *(const f4*)&lf[((size_t)n * CC + c0 + c) * HWP + f * 4];
            h4 o = { (_Float16)v.x, (_Float16)v.y, (_Float16)v.z, (_Float16)v.w };
            *(h4*)&sT[c][f * 4] = o;
        }
        __syncthreads();
        for (int task = tid; task < 8 * HWP; task += 256) {
            int ch = task / HWP, p = task - ch * HWP;
            h8 o;
            #pragma unroll
            for (int cc = 0; cc < 8; cc++) o[cc] = sT[ch * 8 + cc][p];
            *(h8*)&lf16T[((size_t)(n * HWP + p)) * CC + c0 + ch * 8] = o;
        }
    }
}

// ================= hlocF: h_loc = lf16T @ W1[D:], MFMA, frag-layout output =================
__global__ __launch_bounds__(256, 2) void hlocF_kernel(const _Float16* __restrict__ lf16T,
                                                       const _Float16* __restrict__ W1F,
                                                       const float* __restrict__ hpart,
                                                       const float* __restrict__ b1,
                                                       _Float16* __restrict__ g16,
                                                       _Float16* __restrict__ hF) {
    if (blockIdx.x == 196) {
        int kh = blockIdx.y;
        for (int x = threadIdx.x; x < 16 * HID; x += 256) {
            int i = kh * 16 + (x >> 8), k = x & 255;
            float s = b1[k];
            #pragma unroll
            for (int ky = 0; ky < 16; ky++) s += hpart[((size_t)i * 16 + ky) * HID + k];
            g16[(size_t)i * HID + k] = (_Float16)s;
        }
        return;
    }
    __shared__ _Float16 sLf[32][CC + 16];
    int tid = threadIdx.x;
    int w = tid >> 6, l = tid & 63, quad = l >> 4, ln = l & 15;
    int j0 = blockIdx.x * 32;
    int khalf = blockIdx.y;

    #pragma unroll
    for (int s = 0; s < 8; s++) {
        int y = s * 256 + tid;
        int row = y >> 6, col = (y & 63) * 8;
        h8 v = *(const h8*)&lf16T[(size_t)(j0 + row) * CC + col];
        *(h8*)&sLf[row][col] = v;
    }

    F4H8 Af[32];
    {
        const f4* src = (const f4*)W1F + l;
        #pragma unroll
        for (int mt = 0; mt < 2; mt++)
            #pragma unroll
            for (int ks = 0; ks < 16; ks++)
                Af[mt * 16 + ks].f = src[(size_t)((khalf * 8 + w * 2 + mt) * 16 + ks) * 64];
    }
    __syncthreads();

    f4 acc[4] = {};
    #pragma unroll
    for (int ks = 0; ks < 16; ks++) {
        h8 bF[2];
        #pragma unroll
        for (int nt = 0; nt < 2; nt++)
            bF[nt] = *(const h8*)&sLf[nt * 16 + ln][ks * 32 + quad * 8];
        #pragma unroll
        for (int mt = 0; mt < 2; mt++)
            #pragma unroll
            for (int nt = 0; nt < 2; nt++)
                acc[mt * 2 + nt] = __builtin_amdgcn_mfma_f32_16x16x32_f16(Af[mt * 16 + ks].h, bF[nt], acc[mt * 2 + nt], 0, 0, 0);
    }

    #pragma unroll
    for (int mt = 0; mt < 2; mt++)
        #pragma unroll
        for (int nt = 0; nt < 2; nt++)
            #pragma unroll
            for (int r = 0; r < 4; r++) {
                int j  = j0 + nt * 16 + ln;
                int k2 = khalf * 128 + w * 32 + mt * 16 + quad * 4 + r;
                hF[fragIdx(j, k2)] = (_Float16)acc[mt * 2 + nt][r];
            }
}

// ================= score: C[k2][j] = W2^T h1^T + fused epilogue, pipelined staging =================
// grid 1568 = (jg 0..48) x (i 0..31); 512 thr = 8 waves (32 k2 each); 2 j-tiles/block.
// Next tile's hF data prefetched into registers under the current K-loop.
__global__ __launch_bounds__(512, 4) void score_kernel(const _Float16* __restrict__ hF,
                                                       const _Float16* __restrict__ g16,
                                                       const _Float16* __restrict__ W2F,
                                                       const float* __restrict__ b2,
                                                       const float* __restrict__ W3,
                                                       const float* __restrict__ b3,
                                                       float* __restrict__ scores) {
    __shared__ _Float16 sA[64 * HID];     // 32 KB, frag layout
    __shared__ float sRed[64][8];
    int tid = threadIdx.x, w = tid >> 6, l = tid & 63, quad = l >> 4, ln = l & 15;
    int bid = blockIdx.x;
    int i = bid & 31, jg = bid >> 5;      // 0..48

    // W2 A-frags, resident: k2-slice = w*32 .. w*32+31 (16 frags = 64 VGPRs)
    F4H8 Af[16];
    {
        const f4* src = (const f4*)W2F + l;
        #pragma unroll
        for (int mt = 0; mt < 2; mt++)
            #pragma unroll
            for (int ks = 0; ks < 8; ks++)
                Af[mt * 8 + ks].f = src[(size_t)((w * 2 + mt) * 8 + ks) * 64];
    }
    const _Float16* gbase = g16 + (size_t)i * HID;
    float bias3 = b3[0];

    // prologue: prefetch first tile into registers
    h8 r[4];
    {
        const _Float16* hb = hF + (size_t)(jg * 2) * 16384;
        #pragma unroll
        for (int s = 0; s < 4; s++) r[s] = *(const h8*)&hb[(s * 512 + tid) * 8];
    }

    #pragma unroll 1
    for (int t = 0; t < 2; t++) {
        int jt = jg * 2 + t;              // 0..97

        // stage from registers: h1 = relu(r + g) -> LDS
        {
            h8 z = {};
            #pragma unroll
            for (int s = 0; s < 4; s++) {
                int y = s * 512 + tid;     // 0..2047
                h8 gq = *(const h8*)&gbase[(y >> 8) * 32 + ((y >> 4) & 3) * 8];
                *(h8*)&sA[y * 8] = __builtin_elementwise_max(r[s] + gq, z);
            }
        }
        __syncthreads();

        // prefetch next tile (flies under the K-loop; clamped on last tile)
        {
            int jtn = (jt < 97) ? jt + 1 : 97;
            const _Float16* hb = hF + (size_t)jtn * 16384;
            #pragma unroll
            for (int s = 0; s < 4; s++) r[s] = *(const h8*)&hb[(s * 512 + tid) * 8];
        }

        // two nt-passes of 2 j-subtiles each: acc = 4 f4
        #pragma unroll 1
        for (int pass = 0; pass < 2; pass++) {
            f4 acc[4];
            #pragma unroll
            for (int mt = 0; mt < 2; mt++) {
                f4 bv = *(const f4*)&b2[w * 32 + mt * 16 + quad * 4];
                #pragma unroll
                for (int nt = 0; nt < 2; nt++) acc[mt * 2 + nt] = bv;
            }
            #pragma unroll
            for (int ks = 0; ks < 8; ks++) {
                #pragma unroll
                for (int nt = 0; nt < 2; nt++) {
                    int ntg = pass * 2 + nt;
                    h8 hz = *(const h8*)&sA[(ks * 4 + ntg) * 512 + l * 8];
                    #pragma unroll
                    for (int mt = 0; mt < 2; mt++)
                        acc[mt * 2 + nt] = __builtin_amdgcn_mfma_f32_16x16x32_f16(Af[mt * 8 + ks].h, hz, acc[mt * 2 + nt], 0, 0, 0);
                }
            }
            // epilogue partial: relu . W3, reduce over quads
            #pragma unroll
            for (int nt = 0; nt < 2; nt++) {
                float s = 0.f;
                #pragma unroll
                for (int mt = 0; mt < 2; mt++) {
                    f4 w3v = *(const f4*)&W3[w * 32 + mt * 16 + quad * 4];
                    s += fmaxf(acc[mt * 2 + nt][0], 0.f) * w3v.x
                       + fmaxf(acc[mt * 2 + nt][1], 0.f) * w3v.y
                       + fmaxf(acc[mt * 2 + nt][2], 0.f) * w3v.z
                       + fmaxf(acc[mt * 2 + nt][3], 0.f) * w3v.w;
                }
                s += __shfl_xor(s, 16, 64);
                s += __shfl_xor(s, 32, 64);
                if (quad == 0) sRed[(pass * 2 + nt) * 16 + ln][w] = s;
            }
        }
        __syncthreads();
        if (tid < 64) {
            f4 a = *(const f4*)&sRed[tid][0];
            f4 b = *(const f4*)&sRed[tid][4];
            scores[(size_t)i * NHW + jt * 64 + tid] =
                a.x + a.y + a.z + a.w + b.x + b.y + b.z + b.w + bias3;
        }
    }
}

// ================= reduce: per-row max, masked log-mean-exp =================
__global__ __launch_bounds__(1024) void reduce_kernel(const float* __restrict__ scores,
                                                      float* __restrict__ out) {
    int i = blockIdx.x, tid = threadIdx.x;
    const float* row = scores + (size_t)i * NHW;
    const f4* row4 = (const f4*)row;                 // 1568 f4
    __shared__ float sW[16], sW2[16], sval[2];
    float mx = -1e30f;
    for (int q = tid; q < 1568; q += 1024) {
        f4 v = row4[q];
        mx = fmaxf(mx, fmaxf(fmaxf(v.x, v.y), fmaxf(v.z, v.w)));
    }
    #pragma unroll
    for (int off = 32; off > 0; off >>= 1) mx = fmaxf(mx, __shfl_down(mx, off, 64));
    if ((tid & 63) == 0) sW[tid >> 6] = mx;
    __syncthreads();
    if (tid == 0) {
        float m = sW[0];
        for (int c = 1; c < 16; c++) m = fmaxf(m, sW[c]);
        sval[0] = m;
    }
    __syncthreads();
    mx = sval[0];
    int q0 = i * 49, q1 = q0 + 49;
    float tot = 0.f, ownv = 0.f;
    for (int q = tid; q < 1568; q += 1024) {
        f4 v = row4[q];
        float e = expf(v.x - mx) + expf(v.y - mx) + expf(v.z - mx) + expf(v.w - mx);
        tot += e;
        if (q >= q0 && q < q1) ownv += e;
    }
    #pragma unroll
    for (int off = 32; off > 0; off >>= 1) {
        tot  += __shfl_down(tot, off, 64);
        ownv += __shfl_down(ownv, off, 64);
    }
    if ((tid & 63) == 0) { sW[tid >> 6] = tot; sW2[tid >> 6] = ownv; }
    __syncthreads();
    if (tid == 0) {
        float t = 0.f, o = 0.f;
        for (int c = 0; c < 16; c++) { t += sW[c]; o += sW2[c]; }
        float neg_mean = (t - o) / (float)(NHW - HWP) + 1e-10f;
        sval[1] = mx + logf(neg_mean);
    }
    __syncthreads();
    float sub = sval[1];
    if (tid < HWP) out[(size_t)i * HWP + tid] = row[i * HWP + tid] - sub;
}

extern "C" void kernel_launch(void* const* d_in, const int* in_sizes, int n_in,
                              void* d_out, int out_size, void* d_ws, size_t ws_size,
                              hipStream_t stream) {
    const float* lf = (const float*)d_in[0];
    const float* gf = (const float*)d_in[1];
    const float* W1 = (const float*)d_in[2];
    const float* b1 = (const float*)d_in[3];
    const float* W2 = (const float*)d_in[4];
    const float* b2 = (const float*)d_in[5];
    const float* W3 = (const float*)d_in[6];
    const float* b3 = (const float*)d_in[7];
    float* out = (float*)d_out;

    char* ws = (char*)d_ws;
    _Float16* hF     = (_Float16*)ws;                      // 3,211,264 B
    _Float16* g16    = (_Float16*)(ws + 3211264);          // 16 KB
    _Float16* W2F    = (_Float16*)(ws + 3227648);          // 128 KB
    _Float16* W1F    = (_Float16*)(ws + 3358720);          // 256 KB
    _Float16* lf16T  = (_Float16*)(ws + 3620864);          // 6,422,528 B
    float*    scores = (float*)   (ws + 10043392);         // 802,816 B
    float*    hpart  = (float*)   (ws + 10846208);         // 524,288 B

    hipLaunchKernelGGL(prep_kernel, dim3(864), dim3(256), 0, stream,
                       lf, gf, W1, W2, hpart, W2F, W1F, lf16T);
    hipLaunchKernelGGL(hlocF_kernel, dim3(197, 2), dim3(256), 0, stream,
                       lf16T, W1F, hpart, b1, g16, hF);
    hipLaunchKernelGGL(score_kernel, dim3(1568), dim3(512), 0, stream,
                       hF, g16, W2F, b2, W3, b3, scores);
    hipLaunchKernelGGL(reduce_kernel, dim3(NB), dim3(1024), 0, stream, scores, out);
}

// Round 12
// 129.947 us; speedup vs baseline: 1.3840x; 1.1688x over previous
//
#include <hip/hip_runtime.h>
#include <math.h>

#define NB   32
#define CC   512
#define DD   2048
#define HWP  196
#define NHW  6272
#define HID  256

typedef _Float16 h8 __attribute__((ext_vector_type(8)));
typedef _Float16 h4 __attribute__((ext_vector_type(4)));
typedef float    f4 __attribute__((ext_vector_type(4)));
union F4H8 { f4 f; h8 h; };

// fp16 index into fragment-layout tensor for (row j, col k), K=256, 64-row j-tiles.
__device__ __forceinline__ int fragIdx(int j, int k) {
    return ((j >> 6) << 14) + (((k >> 5) * 4 + ((j & 63) >> 4)) << 9)
         + (((((k >> 3) & 3) << 4) + (j & 15)) << 3) + (k & 7);
}

// ================= prep: 864 blocks x 256 =================
// 0..511: hglb partials; 512..607: W2F/W1F frag pack; 608..863: lf transpose
__global__ __launch_bounds__(256) void prep_kernel(const float* __restrict__ lf,
                                                   const float* __restrict__ gf,
                                                   const float* __restrict__ W1,
                                                   const float* __restrict__ W2,
                                                   float* __restrict__ hpart,
                                                   _Float16* __restrict__ W2F,
                                                   _Float16* __restrict__ W1F,
                                                   _Float16* __restrict__ lf16T) {
    int bid = blockIdx.x, tid = threadIdx.x;
    if (bid < 512) {
        int i = bid >> 4, ky = bid & 15, k = tid;
        const float* g = gf + (size_t)i * DD + ky * 128;
        const float* w = W1 + (size_t)(ky * 128) * HID + k;
        float a0 = 0.f, a1 = 0.f, a2 = 0.f, a3 = 0.f;   // 4-way ILP
        #pragma unroll 8
        for (int r = 0; r < 128; r += 4) {
            a0 = fmaf(g[r + 0], w[(size_t)(r + 0) * HID], a0);
            a1 = fmaf(g[r + 1], w[(size_t)(r + 1) * HID], a1);
            a2 = fmaf(g[r + 2], w[(size_t)(r + 2) * HID], a2);
            a3 = fmaf(g[r + 3], w[(size_t)(r + 3) * HID], a3);
        }
        hpart[((size_t)i * 16 + ky) * HID + k] = (a0 + a1) + (a2 + a3);
    } else if (bid < 608) {
        int tg = (bid - 512) * 256 + tid;            // 0..24575
        if (tg < 8192) {
            int t = tg, F = t >> 6, l = t & 63;
            int k2t = F >> 3, ks = F & 7;
            int kb = ks * 32 + (l >> 4) * 8;
            int n  = k2t * 16 + (l & 15);
            _Float16* o = W2F + (size_t)t * 8;
            #pragma unroll
            for (int j = 0; j < 8; j++) o[j] = (_Float16)W2[(size_t)(kb + j) * HID + n];
        } else {
            int t = tg - 8192, F = t >> 6, l = t & 63;
            int k2t = F >> 4, ks = F & 15;
            int kb = ks * 32 + (l >> 4) * 8;
            int n  = k2t * 16 + (l & 15);
            const float* W1c = W1 + (size_t)DD * HID;
            _Float16* o = W1F + (size_t)t * 8;
            #pragma unroll
            for (int j = 0; j < 8; j++) o[j] = (_Float16)W1c[(size_t)(kb + j) * HID + n];
        }
    } else {
        __shared__ _Float16 sT[64][HWP + 4];
        int b = bid - 608;                           // 0..255
        int n = b >> 3, c0 = (b & 7) * 64;
        for (int task = tid; task < 64 * 49; task += 256) {
            int c = task / 49, f = task - c * 49;
            f4 v = *(const f4*)&lf[((size_t)n * CC + c0 + c) * HWP + f * 4];
            h4 o = { (_Float16)v.x, (_Float16)v.y, (_Float16)v.z, (_Float16)v.w };
            *(h4*)&sT[c][f * 4] = o;
        }
        __syncthreads();
        for (int task = tid; task < 8 * HWP; task += 256) {
            int ch = task / HWP, p = task - ch * HWP;
            h8 o;
            #pragma unroll
            for (int cc = 0; cc < 8; cc++) o[cc] = sT[ch * 8 + cc][p];
            *(h8*)&lf16T[((size_t)(n * HWP + p)) * CC + c0 + ch * 8] = o;
        }
    }
}

// ================= hlocF: h_loc = lf16T @ W1[D:], MFMA, frag-layout output =================
__global__ __launch_bounds__(256, 2) void hlocF_kernel(const _Float16* __restrict__ lf16T,
                                                       const _Float16* __restrict__ W1F,
                                                       const float* __restrict__ hpart,
                                                       const float* __restrict__ b1,
                                                       _Float16* __restrict__ g16,
                                                       _Float16* __restrict__ hF) {
    if (blockIdx.x == 196) {
        int kh = blockIdx.y;
        for (int x = threadIdx.x; x < 16 * HID; x += 256) {
            int i = kh * 16 + (x >> 8), k = x & 255;
            float s = b1[k];
            #pragma unroll
            for (int ky = 0; ky < 16; ky++) s += hpart[((size_t)i * 16 + ky) * HID + k];
            g16[(size_t)i * HID + k] = (_Float16)s;
        }
        return;
    }
    __shared__ _Float16 sLf[32][CC + 16];
    int tid = threadIdx.x;
    int w = tid >> 6, l = tid & 63, quad = l >> 4, ln = l & 15;
    int j0 = blockIdx.x * 32;
    int khalf = blockIdx.y;

    #pragma unroll
    for (int s = 0; s < 8; s++) {
        int y = s * 256 + tid;
        int row = y >> 6, col = (y & 63) * 8;
        h8 v = *(const h8*)&lf16T[(size_t)(j0 + row) * CC + col];
        *(h8*)&sLf[row][col] = v;
    }

    F4H8 Af[32];
    {
        const f4* src = (const f4*)W1F + l;
        #pragma unroll
        for (int mt = 0; mt < 2; mt++)
            #pragma unroll
            for (int ks = 0; ks < 16; ks++)
                Af[mt * 16 + ks].f = src[(size_t)((khalf * 8 + w * 2 + mt) * 16 + ks) * 64];
    }
    __syncthreads();

    f4 acc[4] = {};
    #pragma unroll
    for (int ks = 0; ks < 16; ks++) {
        h8 bF[2];
        #pragma unroll
        for (int nt = 0; nt < 2; nt++)
            bF[nt] = *(const h8*)&sLf[nt * 16 + ln][ks * 32 + quad * 8];
        #pragma unroll
        for (int mt = 0; mt < 2; mt++)
            #pragma unroll
            for (int nt = 0; nt < 2; nt++)
                acc[mt * 2 + nt] = __builtin_amdgcn_mfma_f32_16x16x32_f16(Af[mt * 16 + ks].h, bF[nt], acc[mt * 2 + nt], 0, 0, 0);
    }

    #pragma unroll
    for (int mt = 0; mt < 2; mt++)
        #pragma unroll
        for (int nt = 0; nt < 2; nt++)
            #pragma unroll
            for (int r = 0; r < 4; r++) {
                int j  = j0 + nt * 16 + ln;
                int k2 = khalf * 128 + w * 32 + mt * 16 + quad * 4 + r;
                hF[fragIdx(j, k2)] = (_Float16)acc[mt * 2 + nt][r];
            }
}

// ================= score: C[k2][j] = W2^T h1^T + fused epilogue (R8 structure) =================
// grid 1568 = (jg 0..48) x (i 0..31); 512 thr = 8 waves (32 k2 each); 2 j-tiles/block.
// sRed rows padded to 12 dwords (48 B): kills the 16-way bank conflict on epilogue
// writes (12*ln mod 32 -> only free 2-way aliasing), keeps f4 reads 16B-aligned.
__global__ __launch_bounds__(512, 4) void score_kernel(const _Float16* __restrict__ hF,
                                                       const _Float16* __restrict__ g16,
                                                       const _Float16* __restrict__ W2F,
                                                       const float* __restrict__ b2,
                                                       const float* __restrict__ W3,
                                                       const float* __restrict__ b3,
                                                       float* __restrict__ scores) {
    __shared__ _Float16 sA[64 * HID];     // 32 KB, frag layout
    __shared__ float sRed[64][12];        // cols 0..7 used, 4 pad
    int tid = threadIdx.x, w = tid >> 6, l = tid & 63, quad = l >> 4, ln = l & 15;
    int bid = blockIdx.x;
    int i = bid & 31, jg = bid >> 5;      // 0..48

    // W2 A-frags, resident: k2-slice = w*32 .. w*32+31 (16 frags = 64 VGPRs)
    F4H8 Af[16];
    {
        const f4* src = (const f4*)W2F + l;
        #pragma unroll
        for (int mt = 0; mt < 2; mt++)
            #pragma unroll
            for (int ks = 0; ks < 8; ks++)
                Af[mt * 8 + ks].f = src[(size_t)((w * 2 + mt) * 8 + ks) * 64];
    }
    const _Float16* gbase = g16 + (size_t)i * HID;
    float bias3 = b3[0];

    #pragma unroll 1
    for (int t = 0; t < 2; t++) {
        int jt = jg * 2 + t;              // 0..97

        // stage: h1 = relu(hF + g) -> LDS (512 threads, 4 rounds)
        {
            const _Float16* hbase = hF + (size_t)jt * 16384;
            h8 z = {};
            #pragma unroll
            for (int s = 0; s < 4; s++) {
                int y = s * 512 + tid;     // 0..2047
                h8 hv = *(const h8*)&hbase[y * 8];
                h8 gq = *(const h8*)&gbase[(y >> 8) * 32 + ((y >> 4) & 3) * 8];
                h8 hz = __builtin_elementwise_max(hv + gq, z);
                *(h8*)&sA[y * 8] = hz;
            }
        }
        __syncthreads();

        // two nt-passes of 2 j-subtiles each: acc = 4 f4
        #pragma unroll 1
        for (int pass = 0; pass < 2; pass++) {
            f4 acc[4];
            #pragma unroll
            for (int mt = 0; mt < 2; mt++) {
                f4 bv = *(const f4*)&b2[w * 32 + mt * 16 + quad * 4];
                #pragma unroll
                for (int nt = 0; nt < 2; nt++) acc[mt * 2 + nt] = bv;
            }
            #pragma unroll
            for (int ks = 0; ks < 8; ks++) {
                #pragma unroll
                for (int nt = 0; nt < 2; nt++) {
                    int ntg = pass * 2 + nt;
                    h8 hz = *(const h8*)&sA[(ks * 4 + ntg) * 512 + l * 8];
                    #pragma unroll
                    for (int mt = 0; mt < 2; mt++)
                        acc[mt * 2 + nt] = __builtin_amdgcn_mfma_f32_16x16x32_f16(Af[mt * 8 + ks].h, hz, acc[mt * 2 + nt], 0, 0, 0);
                }
            }
            // epilogue partial: relu . W3, reduce over quads
            #pragma unroll
            for (int nt = 0; nt < 2; nt++) {
                float s = 0.f;
                #pragma unroll
                for (int mt = 0; mt < 2; mt++) {
                    f4 w3v = *(const f4*)&W3[w * 32 + mt * 16 + quad * 4];
                    s += fmaxf(acc[mt * 2 + nt][0], 0.f) * w3v.x
                       + fmaxf(acc[mt * 2 + nt][1], 0.f) * w3v.y
                       + fmaxf(acc[mt * 2 + nt][2], 0.f) * w3v.z
                       + fmaxf(acc[mt * 2 + nt][3], 0.f) * w3v.w;
                }
                s += __shfl_xor(s, 16, 64);
                s += __shfl_xor(s, 32, 64);
                if (quad == 0) sRed[(pass * 2 + nt) * 16 + ln][w] = s;
            }
        }
        __syncthreads();
        if (tid < 64) {
            f4 a = *(const f4*)&sRed[tid][0];
            f4 b = *(const f4*)&sRed[tid][4];
            scores[(size_t)i * NHW + jt * 64 + tid] =
                a.x + a.y + a.z + a.w + b.x + b.y + b.z + b.w + bias3;
        }
    }
}

// ================= reduce: per-row max, masked log-mean-exp =================
__global__ __launch_bounds__(1024) void reduce_kernel(const float* __restrict__ scores,
                                                      float* __restrict__ out) {
    int i = blockIdx.x, tid = threadIdx.x;
    const float* row = scores + (size_t)i * NHW;
    const f4* row4 = (const f4*)row;                 // 1568 f4
    __shared__ float sW[16], sW2[16], sval[2];
    float mx = -1e30f;
    for (int q = tid; q < 1568; q += 1024) {
        f4 v = row4[q];
        mx = fmaxf(mx, fmaxf(fmaxf(v.x, v.y), fmaxf(v.z, v.w)));
    }
    #pragma unroll
    for (int off = 32; off > 0; off >>= 1) mx = fmaxf(mx, __shfl_down(mx, off, 64));
    if ((tid & 63) == 0) sW[tid >> 6] = mx;
    __syncthreads();
    if (tid == 0) {
        float m = sW[0];
        for (int c = 1; c < 16; c++) m = fmaxf(m, sW[c]);
        sval[0] = m;
    }
    __syncthreads();
    mx = sval[0];
    int q0 = i * 49, q1 = q0 + 49;
    float tot = 0.f, ownv = 0.f;
    for (int q = tid; q < 1568; q += 1024) {
        f4 v = row4[q];
        float e = expf(v.x - mx) + expf(v.y - mx) + expf(v.z - mx) + expf(v.w - mx);
        tot += e;
        if (q >= q0 && q < q1) ownv += e;
    }
    #pragma unroll
    for (int off = 32; off > 0; off >>= 1) {
        tot  += __shfl_down(tot, off, 64);
        ownv += __shfl_down(ownv, off, 64);
    }
    if ((tid & 63) == 0) { sW[tid >> 6] = tot; sW2[tid >> 6] = ownv; }
    __syncthreads();
    if (tid == 0) {
        float t = 0.f, o = 0.f;
        for (int c = 0; c < 16; c++) { t += sW[c]; o += sW2[c]; }
        float neg_mean = (t - o) / (float)(NHW - HWP) + 1e-10f;
        sval[1] = mx + logf(neg_mean);
    }
    __syncthreads();
    float sub = sval[1];
    if (tid < HWP) out[(size_t)i * HWP + tid] = row[i * HWP + tid] - sub;
}

extern "C" void kernel_launch(void* const* d_in, const int* in_sizes, int n_in,
                              void* d_out, int out_size, void* d_ws, size_t ws_size,
                              hipStream_t stream) {
    const float* lf = (const float*)d_in[0];
    const float* gf = (const float*)d_in[1];
    const float* W1 = (const float*)d_in[2];
    const float* b1 = (const float*)d_in[3];
    const float* W2 = (const float*)d_in[4];
    const float* b2 = (const float*)d_in[5];
    const float* W3 = (const float*)d_in[6];
    const float* b3 = (const float*)d_in[7];
    float* out = (float*)d_out;

    char* ws = (char*)d_ws;
    _Float16* hF     = (_Float16*)ws;                      // 3,211,264 B
    _Float16* g16    = (_Float16*)(ws + 3211264);          // 16 KB
    _Float16* W2F    = (_Float16*)(ws + 3227648);          // 128 KB
    _Float16* W1F    = (_Float16*)(ws + 3358720);          // 256 KB
    _Float16* lf16T  = (_Float16*)(ws + 3620864);          // 6,422,528 B
    float*    scores = (float*)   (ws + 10043392);         // 802,816 B
    float*    hpart  = (float*)   (ws + 10846208);         // 524,288 B

    hipLaunchKernelGGL(prep_kernel, dim3(864), dim3(256), 0, stream,
                       lf, gf, W1, W2, hpart, W2F, W1F, lf16T);
    hipLaunchKernelGGL(hlocF_kernel, dim3(197, 2), dim3(256), 0, stream,
                       lf16T, W1F, hpart, b1, g16, hF);
    hipLaunchKernelGGL(score_kernel, dim3(1568), dim3(512), 0, stream,
                       hF, g16, W2F, b2, W3, b3, scores);
    hipLaunchKernelGGL(reduce_kernel, dim3(NB), dim3(1024), 0, stream, scores, out);
}

// Round 13
// 122.206 us; speedup vs baseline: 1.4716x; 1.0633x over previous
//
#include <hip/hip_runtime.h>
#include <math.h>

#define NB   32
#define CC   512
#define DD   2048
#define HWP  196
#define NHW  6272
#define HID  256

typedef _Float16 h8 __attribute__((ext_vector_type(8)));
typedef _Float16 h4 __attribute__((ext_vector_type(4)));
typedef float    f4 __attribute__((ext_vector_type(4)));
union F4H8 { f4 f; h8 h; };

// fp16 index into fragment-layout tensor for (row j, col k), K=256, 64-row j-tiles.
__device__ __forceinline__ int fragIdx(int j, int k) {
    return ((j >> 6) << 14) + (((k >> 5) * 4 + ((j & 63) >> 4)) << 9)
         + (((((k >> 3) & 3) << 4) + (j & 15)) << 3) + (k & 7);
}

// ================= prep: 864 blocks x 256 =================
// 0..511: hglb partials; 512..607: W2F/W1F frag pack; 608..863: lf transpose
__global__ __launch_bounds__(256) void prep_kernel(const float* __restrict__ lf,
                                                   const float* __restrict__ gf,
                                                   const float* __restrict__ W1,
                                                   const float* __restrict__ W2,
                                                   float* __restrict__ hpart,
                                                   _Float16* __restrict__ W2F,
                                                   _Float16* __restrict__ W1F,
                                                   _Float16* __restrict__ lf16T) {
    int bid = blockIdx.x, tid = threadIdx.x;
    if (bid < 512) {
        int i = bid >> 4, ky = bid & 15, k = tid;
        const float* g = gf + (size_t)i * DD + ky * 128;
        const float* w = W1 + (size_t)(ky * 128) * HID + k;
        float a0 = 0.f, a1 = 0.f, a2 = 0.f, a3 = 0.f;   // 4-way ILP
        #pragma unroll 8
        for (int r = 0; r < 128; r += 4) {
            a0 = fmaf(g[r + 0], w[(size_t)(r + 0) * HID], a0);
            a1 = fmaf(g[r + 1], w[(size_t)(r + 1) * HID], a1);
            a2 = fmaf(g[r + 2], w[(size_t)(r + 2) * HID], a2);
            a3 = fmaf(g[r + 3], w[(size_t)(r + 3) * HID], a3);
        }
        hpart[((size_t)i * 16 + ky) * HID + k] = (a0 + a1) + (a2 + a3);
    } else if (bid < 608) {
        int tg = (bid - 512) * 256 + tid;            // 0..24575
        if (tg < 8192) {
            int t = tg, F = t >> 6, l = t & 63;
            int k2t = F >> 3, ks = F & 7;
            int kb = ks * 32 + (l >> 4) * 8;
            int n  = k2t * 16 + (l & 15);
            _Float16* o = W2F + (size_t)t * 8;
            #pragma unroll
            for (int j = 0; j < 8; j++) o[j] = (_Float16)W2[(size_t)(kb + j) * HID + n];
        } else {
            int t = tg - 8192, F = t >> 6, l = t & 63;
            int k2t = F >> 4, ks = F & 15;
            int kb = ks * 32 + (l >> 4) * 8;
            int n  = k2t * 16 + (l & 15);
            const float* W1c = W1 + (size_t)DD * HID;
            _Float16* o = W1F + (size_t)t * 8;
            #pragma unroll
            for (int j = 0; j < 8; j++) o[j] = (_Float16)W1c[(size_t)(kb + j) * HID + n];
        }
    } else {
        __shared__ _Float16 sT[64][HWP + 4];
        int b = bid - 608;                           // 0..255
        int n = b >> 3, c0 = (b & 7) * 64;
        for (int task = tid; task < 64 * 49; task += 256) {
            int c = task / 49, f = task - c * 49;
            f4 v = *(const f4*)&lf[((size_t)n * CC + c0 + c) * HWP + f * 4];
            h4 o = { (_Float16)v.x, (_Float16)v.y, (_Float16)v.z, (_Float16)v.w };
            *(h4*)&sT[c][f * 4] = o;
        }
        __syncthreads();
        for (int task = tid; task < 8 * HWP; task += 256) {
            int ch = task / HWP, p = task - ch * HWP;
            h8 o;
            #pragma unroll
            for (int cc = 0; cc < 8; cc++) o[cc] = sT[ch * 8 + cc][p];
            *(h8*)&lf16T[((size_t)(n * HWP + p)) * CC + c0 + ch * 8] = o;
        }
    }
}

// ================= hlocF: h_loc = lf16T @ W1[D:], MFMA, frag-layout output =================
__global__ __launch_bounds__(256, 2) void hlocF_kernel(const _Float16* __restrict__ lf16T,
                                                       const _Float16* __restrict__ W1F,
                                                       const float* __restrict__ hpart,
                                                       const float* __restrict__ b1,
                                                       _Float16* __restrict__ g16,
                                                       _Float16* __restrict__ hF) {
    if (blockIdx.x == 196) {
        int kh = blockIdx.y;
        for (int x = threadIdx.x; x < 16 * HID; x += 256) {
            int i = kh * 16 + (x >> 8), k = x & 255;
            float s = b1[k];
            #pragma unroll
            for (int ky = 0; ky < 16; ky++) s += hpart[((size_t)i * 16 + ky) * HID + k];
            g16[(size_t)i * HID + k] = (_Float16)s;
        }
        return;
    }
    __shared__ _Float16 sLf[32][CC + 16];
    int tid = threadIdx.x;
    int w = tid >> 6, l = tid & 63, quad = l >> 4, ln = l & 15;
    int j0 = blockIdx.x * 32;
    int khalf = blockIdx.y;

    #pragma unroll
    for (int s = 0; s < 8; s++) {
        int y = s * 256 + tid;
        int row = y >> 6, col = (y & 63) * 8;
        h8 v = *(const h8*)&lf16T[(size_t)(j0 + row) * CC + col];
        *(h8*)&sLf[row][col] = v;
    }

    F4H8 Af[32];
    {
        const f4* src = (const f4*)W1F + l;
        #pragma unroll
        for (int mt = 0; mt < 2; mt++)
            #pragma unroll
            for (int ks = 0; ks < 16; ks++)
                Af[mt * 16 + ks].f = src[(size_t)((khalf * 8 + w * 2 + mt) * 16 + ks) * 64];
    }
    __syncthreads();

    f4 acc[4] = {};
    #pragma unroll
    for (int ks = 0; ks < 16; ks++) {
        h8 bF[2];
        #pragma unroll
        for (int nt = 0; nt < 2; nt++)
            bF[nt] = *(const h8*)&sLf[nt * 16 + ln][ks * 32 + quad * 8];
        #pragma unroll
        for (int mt = 0; mt < 2; mt++)
            #pragma unroll
            for (int nt = 0; nt < 2; nt++)
                acc[mt * 2 + nt] = __builtin_amdgcn_mfma_f32_16x16x32_f16(Af[mt * 16 + ks].h, bF[nt], acc[mt * 2 + nt], 0, 0, 0);
    }

    #pragma unroll
    for (int mt = 0; mt < 2; mt++)
        #pragma unroll
        for (int nt = 0; nt < 2; nt++)
            #pragma unroll
            for (int r = 0; r < 4; r++) {
                int j  = j0 + nt * 16 + ln;
                int k2 = khalf * 128 + w * 32 + mt * 16 + quad * 4 + r;
                hF[fragIdx(j, k2)] = (_Float16)acc[mt * 2 + nt][r];
            }
}

// ================= score: C[k2][j] = W2^T h1^T + fused epilogue, 128-j tile =================
// grid 1568 = (jt 0..48) x (i 0..31); 512 thr = 8 waves (32 k2 each); ONE 128-j tile/block.
// sA = two concatenated 64-j hF tiles (64 KB). 2 barriers/block total; 128 MFMAs/wave
// between barriers. Occupancy unchanged vs R12 (wave-capped at 2 blocks/CU; 2x70KB fits).
__global__ __launch_bounds__(512, 4) void score_kernel(const _Float16* __restrict__ hF,
                                                       const _Float16* __restrict__ g16,
                                                       const _Float16* __restrict__ W2F,
                                                       const float* __restrict__ b2,
                                                       const float* __restrict__ W3,
                                                       const float* __restrict__ b3,
                                                       float* __restrict__ scores) {
    __shared__ _Float16 sA[128 * HID];    // 64 KB: [0..16383]=tile 2*jt, [16384..]=tile 2*jt+1
    __shared__ float sRed[128][12];       // cols 0..7 used, pad to 12 dwords (48 B rows)
    int tid = threadIdx.x, w = tid >> 6, l = tid & 63, quad = l >> 4, ln = l & 15;
    int bid = blockIdx.x;
    int i = bid & 31, jt = bid >> 5;      // jt 0..48 (tile of 128 j)

    // W2 A-frags, resident: k2-slice = w*32 .. w*32+31 (16 frags = 64 VGPRs)
    F4H8 Af[16];
    {
        const f4* src = (const f4*)W2F + l;
        #pragma unroll
        for (int mt = 0; mt < 2; mt++)
            #pragma unroll
            for (int ks = 0; ks < 8; ks++)
                Af[mt * 8 + ks].f = src[(size_t)((w * 2 + mt) * 8 + ks) * 64];
    }
    const _Float16* gbase = g16 + (size_t)i * HID;
    float bias3 = b3[0];

    // stage: h1 = relu(hF + g) -> LDS, both 64-j subtiles (8 rounds x 512 thr x 16 B)
    {
        const _Float16* hbase = hF + (size_t)(jt * 2) * 16384;
        h8 z = {};
        #pragma unroll
        for (int s = 0; s < 8; s++) {
            int y  = s * 512 + tid;        // 0..4095
            int y2 = y & 2047;             // position within the 64-j subtile
            h8 hv = *(const h8*)&hbase[y * 8];
            h8 gq = *(const h8*)&gbase[(y2 >> 8) * 32 + ((y2 >> 4) & 3) * 8];
            *(h8*)&sA[y * 8] = __builtin_elementwise_max(hv + gq, z);
        }
    }
    __syncthreads();

    // four nt-passes of 2 j-subtiles each: acc = 4 f4 (16 regs)
    #pragma unroll 1
    for (int pass = 0; pass < 4; pass++) {
        f4 acc[4];
        #pragma unroll
        for (int mt = 0; mt < 2; mt++) {
            f4 bv = *(const f4*)&b2[w * 32 + mt * 16 + quad * 4];
            #pragma unroll
            for (int nt = 0; nt < 2; nt++) acc[mt * 2 + nt] = bv;
        }
        #pragma unroll
        for (int ks = 0; ks < 8; ks++) {
            #pragma unroll
            for (int nt = 0; nt < 2; nt++) {
                int ntg = pass * 2 + nt;   // 0..7 across 128 j
                int base = (ntg >= 4) ? 16384 + (ks * 4 + (ntg - 4)) * 512
                                      : (ks * 4 + ntg) * 512;
                h8 hz = *(const h8*)&sA[base + l * 8];
                #pragma unroll
                for (int mt = 0; mt < 2; mt++)
                    acc[mt * 2 + nt] = __builtin_amdgcn_mfma_f32_16x16x32_f16(Af[mt * 8 + ks].h, hz, acc[mt * 2 + nt], 0, 0, 0);
            }
        }
        // epilogue partial: relu . W3, reduce over quads
        #pragma unroll
        for (int nt = 0; nt < 2; nt++) {
            float s = 0.f;
            #pragma unroll
            for (int mt = 0; mt < 2; mt++) {
                f4 w3v = *(const f4*)&W3[w * 32 + mt * 16 + quad * 4];
                s += fmaxf(acc[mt * 2 + nt][0], 0.f) * w3v.x
                   + fmaxf(acc[mt * 2 + nt][1], 0.f) * w3v.y
                   + fmaxf(acc[mt * 2 + nt][2], 0.f) * w3v.z
                   + fmaxf(acc[mt * 2 + nt][3], 0.f) * w3v.w;
            }
            s += __shfl_xor(s, 16, 64);
            s += __shfl_xor(s, 32, 64);
            if (quad == 0) sRed[(pass * 2 + nt) * 16 + ln][w] = s;
        }
    }
    __syncthreads();
    if (tid < 128) {
        f4 a = *(const f4*)&sRed[tid][0];
        f4 b = *(const f4*)&sRed[tid][4];
        scores[(size_t)i * NHW + jt * 128 + tid] =
            a.x + a.y + a.z + a.w + b.x + b.y + b.z + b.w + bias3;
    }
}

// ================= reduce: per-row max, masked log-mean-exp =================
__global__ __launch_bounds__(1024) void reduce_kernel(const float* __restrict__ scores,
                                                      float* __restrict__ out) {
    int i = blockIdx.x, tid = threadIdx.x;
    const float* row = scores + (size_t)i * NHW;
    const f4* row4 = (const f4*)row;                 // 1568 f4
    __shared__ float sW[16], sW2[16], sval[2];
    float mx = -1e30f;
    for (int q = tid; q < 1568; q += 1024) {
        f4 v = row4[q];
        mx = fmaxf(mx, fmaxf(fmaxf(v.x, v.y), fmaxf(v.z, v.w)));
    }
    #pragma unroll
    for (int off = 32; off > 0; off >>= 1) mx = fmaxf(mx, __shfl_down(mx, off, 64));
    if ((tid & 63) == 0) sW[tid >> 6] = mx;
    __syncthreads();
    if (tid == 0) {
        float m = sW[0];
        for (int c = 1; c < 16; c++) m = fmaxf(m, sW[c]);
        sval[0] = m;
    }
    __syncthreads();
    mx = sval[0];
    int q0 = i * 49, q1 = q0 + 49;
    float tot = 0.f, ownv = 0.f;
    for (int q = tid; q < 1568; q += 1024) {
        f4 v = row4[q];
        float e = expf(v.x - mx) + expf(v.y - mx) + expf(v.z - mx) + expf(v.w - mx);
        tot += e;
        if (q >= q0 && q < q1) ownv += e;
    }
    #pragma unroll
    for (int off = 32; off > 0; off >>= 1) {
        tot  += __shfl_down(tot, off, 64);
        ownv += __shfl_down(ownv, off, 64);
    }
    if ((tid & 63) == 0) { sW[tid >> 6] = tot; sW2[tid >> 6] = ownv; }
    __syncthreads();
    if (tid == 0) {
        float t = 0.f, o = 0.f;
        for (int c = 0; c < 16; c++) { t += sW[c]; o += sW2[c]; }
        float neg_mean = (t - o) / (float)(NHW - HWP) + 1e-10f;
        sval[1] = mx + logf(neg_mean);
    }
    __syncthreads();
    float sub = sval[1];
    if (tid < HWP) out[(size_t)i * HWP + tid] = row[i * HWP + tid] - sub;
}

extern "C" void kernel_launch(void* const* d_in, const int* in_sizes, int n_in,
                              void* d_out, int out_size, void* d_ws, size_t ws_size,
                              hipStream_t stream) {
    const float* lf = (const float*)d_in[0];
    const float* gf = (const float*)d_in[1];
    const float* W1 = (const float*)d_in[2];
    const float* b1 = (const float*)d_in[3];
    const float* W2 = (const float*)d_in[4];
    const float* b2 = (const float*)d_in[5];
    const float* W3 = (const float*)d_in[6];
    const float* b3 = (const float*)d_in[7];
    float* out = (float*)d_out;

    char* ws = (char*)d_ws;
    _Float16* hF     = (_Float16*)ws;                      // 3,211,264 B
    _Float16* g16    = (_Float16*)(ws + 3211264);          // 16 KB
    _Float16* W2F    = (_Float16*)(ws + 3227648);          // 128 KB
    _Float16* W1F    = (_Float16*)(ws + 3358720);          // 256 KB
    _Float16* lf16T  = (_Float16*)(ws + 3620864);          // 6,422,528 B
    float*    scores = (float*)   (ws + 10043392);         // 802,816 B
    float*    hpart  = (float*)   (ws + 10846208);         // 524,288 B

    hipLaunchKernelGGL(prep_kernel, dim3(864), dim3(256), 0, stream,
                       lf, gf, W1, W2, hpart, W2F, W1F, lf16T);
    hipLaunchKernelGGL(hlocF_kernel, dim3(197, 2), dim3(256), 0, stream,
                       lf16T, W1F, hpart, b1, g16, hF);
    hipLaunchKernelGGL(score_kernel, dim3(1568), dim3(512), 0, stream,
                       hF, g16, W2F, b2, W3, b3, scores);
    hipLaunchKernelGGL(reduce_kernel, dim3(NB), dim3(1024), 0, stream, scores, out);
}